// Round 8
// baseline (214.237 us; speedup 1.0000x reference)
//
#include <hip/hip_runtime.h>
#include <math.h>

#define L_SEQ 32768
#define PL 16384    // u16 per LDS plane (128 x 128, stride 128, XOR-swizzled)
#define GP 16384    // u16 per global plane (stride 128, plain)

typedef unsigned short u16;
typedef float f32x4 __attribute__((ext_vector_type(4)));
typedef short bf16x8 __attribute__((ext_vector_type(8)));
typedef u16 u16x4 __attribute__((ext_vector_type(4)));

__device__ __forceinline__ u16 f2bf(float x) {
  unsigned u = __float_as_uint(x);
  u = u + 0x7FFFu + ((u >> 16) & 1u);
  return (u16)(u >> 16);
}
__device__ __forceinline__ float bf2f(u16 h) {
  return __uint_as_float(((unsigned)h) << 16);
}
// XOR-swizzled LDS index: row r, col c (u16 units). Keeps 8-u16 (16B) blocks
// intact; spreads the 8 rows of a stripe across 8 bank groups -> b128 reads
// at fixed col across consecutive rows are conflict-free (8-phase minimum).
__device__ __forceinline__ int MIDX(int r, int c) {
  return (r << 7) + (c ^ ((r & 7) << 3));
}
__device__ __forceinline__ f32x4 MF(bf16x8 a, bf16x8 b, f32x4 c) {
  return __builtin_amdgcn_mfma_f32_16x16x32_bf16(a, b, c, 0, 0, 0);
}

// ---------------------------------------------------------------------------
// One product step on a 1024-thread block: C = A(128x128) * B(128xN), Mrows.
// fp32 emulated by 3 bf16 MFMAs (hh+hl+lh) on separate hi/lo planes.
// 16 waves, 32x32 tiles; 2-stage ds_read->MFMA software pipeline.
// acc = normal tile (lane: col cc, rows rb..rb+3)  -> col-major outputs
// accT = mfma(B,A) = transposed tile (lane: row rr, cols cb..cb+3) -> row-major
// ASRC: 0 = LDS M planes (swizzled) | 1 = global rows (gA, stride 128, +aPl)
// BSRC: 0 = LDS Bt planes (swizzled) | 1 = global transposed rows (gB, +bPl)
// OUTM: 0 none | 2 write M (accT) AND Bt (acc) in-place
// OUTG: 0 none | 1 rows gO[(gOrow0+rr)*128+cb], mask rr<Mrows (accT)
//       2 transposed gO[(gOrow0+cc)*128+rb], mask cc<N (acc)
//       3 both: gO rows + gO2 transposed (U12 spill)
// MODE: 0 none | 2 +=T(gE rows)+T2(LDS)+I | 4 v=c3*(v+U12)-I (gE rows/gEt)
// ---------------------------------------------------------------------------
template<int ASRC,int BSRC,int OUTM,int OUTG,int MODE>
__device__ void mm(u16* lds, const u16* gA, int aPl, const u16* gB, int bPl,
                   u16* gO, int oPl, int gOrow0, u16* gO2,
                   int Mrows, int N, float c3, const u16* gE, const u16* gEt) {
  u16* Mh = lds;          u16* Ml = lds + PL;
  u16* Th = lds + 2 * PL; u16* Tl = lds + 3 * PL;
  const int t = threadIdx.x, lane = t & 63;
  const int la = lane & 15, g = lane >> 4;
  const int w = t >> 6;
  const int r0 = (w >> 2) << 5, c0 = (w & 3) << 5;
  constexpr bool doA = (OUTM == 2) || (OUTG == 2) || (OUTG == 3);
  constexpr bool doT = (OUTM == 2) || (OUTG == 1) || (OUTG == 3);
  const bool act = (r0 < Mrows) && (c0 < N);

  __syncthreads();  // prior step's LDS/global writes visible

  f32x4 acc[2][2], accT[2][2];
#pragma unroll
  for (int i = 0; i < 2; ++i)
#pragma unroll
    for (int j = 0; j < 2; ++j) {
      acc[i][j] = (f32x4){0.f, 0.f, 0.f, 0.f};
      accT[i][j] = (f32x4){0.f, 0.f, 0.f, 0.f};
    }

  if (act) {
    bf16x8 Ah[2][2], Al[2][2], Bh[2][2], Bl[2][2];  // [stage][frag]
    auto load_stage = [&](int kb, int s) {
      const int kp = (kb << 5) + (g << 3);
#pragma unroll
      for (int fr = 0; fr < 2; ++fr) {
        const int ar = r0 + (fr << 4) + la;
        if constexpr (ASRC == 0) {
          Ah[s][fr] = *(const bf16x8*)(Mh + MIDX(ar, kp));
          Al[s][fr] = *(const bf16x8*)(Ml + MIDX(ar, kp));
        } else {
          Ah[s][fr] = *(const bf16x8*)(gA + ar * 128 + kp);
          Al[s][fr] = *(const bf16x8*)(gA + aPl + ar * 128 + kp);
        }
      }
#pragma unroll
      for (int fc = 0; fc < 2; ++fc) {
        const int bc = c0 + (fc << 4) + la;
        if constexpr (BSRC == 0) {
          Bh[s][fc] = *(const bf16x8*)(Th + MIDX(bc, kp));
          Bl[s][fc] = *(const bf16x8*)(Tl + MIDX(bc, kp));
        } else {
          Bh[s][fc] = *(const bf16x8*)(gB + bc * 128 + kp);
          Bl[s][fc] = *(const bf16x8*)(gB + bPl + bc * 128 + kp);
        }
      }
    };
    load_stage(0, 0);
#pragma unroll
    for (int kb = 0; kb < 4; ++kb) {
      const int cur = kb & 1;
      if (kb < 3) load_stage(kb + 1, cur ^ 1);  // prefetch next K-block
#pragma unroll
      for (int fr = 0; fr < 2; ++fr)
#pragma unroll
        for (int fc = 0; fc < 2; ++fc) {
          if constexpr (doA) {
            acc[fr][fc] = MF(Ah[cur][fr], Bh[cur][fc], acc[fr][fc]);
            acc[fr][fc] = MF(Ah[cur][fr], Bl[cur][fc], acc[fr][fc]);
            acc[fr][fc] = MF(Al[cur][fr], Bh[cur][fc], acc[fr][fc]);
          }
          if constexpr (doT) {
            accT[fr][fc] = MF(Bh[cur][fc], Ah[cur][fr], accT[fr][fc]);
            accT[fr][fc] = MF(Bh[cur][fc], Al[cur][fr], accT[fr][fc]);
            accT[fr][fc] = MF(Bl[cur][fc], Ah[cur][fr], accT[fr][fc]);
          }
        }
    }
  }

  // in-place LDS overwrite needs a read-drain barrier; global-only steps don't
  if constexpr (OUTM == 2) __syncthreads();

  if (!act) return;

  if constexpr (doT) {
    // accT: lane holds C[rr][cb..cb+3]
#pragma unroll
    for (int fr = 0; fr < 2; ++fr)
#pragma unroll
      for (int fc = 0; fc < 2; ++fc) {
        const int rr = r0 + (fr << 4) + la;
        const int cb = c0 + (fc << 4) + (g << 2);
        float v[4];
#pragma unroll
        for (int j = 0; j < 4; ++j) v[j] = accT[fr][fc][j];
        if constexpr (MODE == 2) {
#pragma unroll
          for (int j = 0; j < 4; ++j)
            v[j] += bf2f(gE[rr * 128 + cb + j]) + bf2f(gE[GP + rr * 128 + cb + j])
                  + bf2f(Mh[MIDX(rr, cb + j)]) + bf2f(Ml[MIDX(rr, cb + j)])
                  + ((rr == cb + j) ? 1.f : 0.f);
        }
        if constexpr (MODE == 4) {
#pragma unroll
          for (int j = 0; j < 4; ++j)
            v[j] = c3 * (v[j] + bf2f(gE[rr * 128 + cb + j]) +
                         bf2f(gE[GP + rr * 128 + cb + j])) -
                   ((rr == cb + j) ? 1.f : 0.f);
        }
        u16x4 hi, lo;
#pragma unroll
        for (int j = 0; j < 4; ++j) {
          u16 h = f2bf(v[j]); hi[j] = h; lo[j] = f2bf(v[j] - bf2f(h));
        }
        if constexpr (OUTM == 2) {
          *(u16x4*)(Mh + MIDX(rr, cb)) = hi;
          *(u16x4*)(Ml + MIDX(rr, cb)) = lo;
        }
        if constexpr (OUTG == 1) {
          if (rr < Mrows) {
            *(u16x4*)(gO + (gOrow0 + rr) * 128 + cb) = hi;
            *(u16x4*)(gO + oPl + (gOrow0 + rr) * 128 + cb) = lo;
          }
        }
        if constexpr (OUTG == 3) {
          *(u16x4*)(gO + rr * 128 + cb) = hi;
          *(u16x4*)(gO + oPl + rr * 128 + cb) = lo;
        }
      }
  }
  if constexpr (doA) {
    // acc: lane holds C[rb..rb+3][cc]
#pragma unroll
    for (int fr = 0; fr < 2; ++fr)
#pragma unroll
      for (int fc = 0; fc < 2; ++fc) {
        const int cc = c0 + (fc << 4) + la;
        const int rb = r0 + (fr << 4) + (g << 2);
        float v[4];
#pragma unroll
        for (int j = 0; j < 4; ++j) v[j] = acc[fr][fc][j];
        if constexpr (MODE == 2) {
#pragma unroll
          for (int j = 0; j < 4; ++j)
            v[j] += bf2f(gE[(rb + j) * 128 + cc]) + bf2f(gE[GP + (rb + j) * 128 + cc])
                  + bf2f(Th[MIDX(cc, rb + j)]) + bf2f(Tl[MIDX(cc, rb + j)])
                  + ((rb + j == cc) ? 1.f : 0.f);
        }
        if constexpr (MODE == 4) {
#pragma unroll
          for (int j = 0; j < 4; ++j)
            v[j] = c3 * (v[j] + bf2f(gEt[cc * 128 + rb + j]) +
                         bf2f(gEt[GP + cc * 128 + rb + j])) -
                   ((rb + j == cc) ? 1.f : 0.f);
        }
        u16x4 hi, lo;
#pragma unroll
        for (int j = 0; j < 4; ++j) {
          u16 h = f2bf(v[j]); hi[j] = h; lo[j] = f2bf(v[j] - bf2f(h));
        }
        if constexpr (OUTM == 2) {
          *(u16x4*)(Th + MIDX(cc, rb)) = hi;
          *(u16x4*)(Tl + MIDX(cc, rb)) = lo;
        }
        if constexpr (OUTG == 2) {
          if (cc < N) {
            *(u16x4*)(gO + (gOrow0 + cc) * 128 + rb) = hi;
            *(u16x4*)(gO + oPl + (gOrow0 + cc) * 128 + rb) = lo;
          }
        }
        if constexpr (OUTG == 3) {
          *(u16x4*)(gO2 + cc * 128 + rb) = hi;
          *(u16x4*)(gO2 + oPl + cc * 128 + rb) = lo;
        }
      }
  }
}

// ---------------------------------------------------------------------------
// Chain: 2 independent 1024-thread blocks (16 waves = 4/SIMD).
// Neumann (4 products): T2 -> U12(spill) -> T4 -> ab = c3*(U12*T4+U12)-I
// block 0: R-cols doubling (rt = R^T, 256x128 global planes), 8 dbl + 7 sq
// block 1: S-rows doubling (gs, 128x128 global planes), 14 sq + 7 dbl
// All global arrays plain row-major; LDS planes XOR-swizzled.
// ---------------------------------------------------------------------------
__global__ void __launch_bounds__(1024, 4) chain_k(const float* __restrict__ A,
                                                   const float* __restrict__ Bv,
                                                   const float* __restrict__ Cv,
                                                   const float* __restrict__ lstep,
                                                   u16* ws) {
  extern __shared__ u16 lds[];
  const int bid = blockIdx.x;
  u16* gT    = ws + bid * 131072;  // per-block spills: T rows (2 planes)
  u16* gU12  = gT + 32768;         // U12 rows (2 planes)
  u16* gU12t = gT + 65536;         // U12 transposed (2 planes)
  u16* rt = ws + 262144;           // R^T: 256 x 128, hi plane; lo at +32768
  u16* gs = ws + 327680;           // S rows: 128 x 128, hi; lo at +GP

  const int t = threadIdx.x;
  const float step = expf(lstep[0]);
  const float alpha = 0.5f * step / (1.f + step);
  const float c3 = 2.f / (1.f + step);
  u16* Mh = lds; u16* Ml = lds + PL; u16* Th = lds + 2 * PL; u16* Tl = lds + 3 * PL;

  // s0: T = alpha*(A+2I) -> LDS M rows + LDS Bt cols (swizzled), global gT rows
#pragma unroll
  for (int i = 0; i < 4; ++i) {
    int e4 = (t + (i << 10)) << 2;
    int r = e4 >> 7, c = e4 & 127;
    float4 av = *(const float4*)(A + e4);
    float vv[4] = {av.x, av.y, av.z, av.w};
    u16x4 hi, lo;
#pragma unroll
    for (int j = 0; j < 4; ++j) {
      float v = alpha * (vv[j] + ((r == c + j) ? 2.f : 0.f));
      u16 h = f2bf(v); hi[j] = h; lo[j] = f2bf(v - bf2f(h));
    }
    *(u16x4*)(Mh + MIDX(r, c)) = hi;
    *(u16x4*)(Ml + MIDX(r, c)) = lo;
    *(u16x4*)(gT + r * 128 + c) = hi;
    *(u16x4*)(gT + GP + r * 128 + c) = lo;
#pragma unroll
    for (int j = 0; j < 4; ++j) {
      Th[MIDX(c + j, r)] = hi[j];
      Tl[MIDX(c + j, r)] = lo[j];
    }
  }

  // Neumann
  mm<0,0,2,0,0>(lds, 0,0, 0,0, 0,0,0,0, 128,128, 0.f, 0,0);                 // M,Bt = T2
  mm<1,0,0,3,2>(lds, gT,GP, 0,0, gU12,GP,0,gU12t, 128,128, 0.f, gT,0);      // U12 spill
  mm<0,0,2,0,0>(lds, 0,0, 0,0, 0,0,0,0, 128,128, 0.f, 0,0);                 // M,Bt = T4
  mm<1,0,2,0,4>(lds, gU12,GP, 0,0, 0,0,0,0, 128,128, c3, gU12,gU12t);       // M,Bt = ab

  if (bid == 0) {
    __syncthreads();
    if (t < 128) {  // bb = (step/2)*(ab*B + B) -> rt row 0
      float a2 = 0.f;
      for (int p = 0; p < 128; ++p)
        a2 = fmaf(bf2f(Mh[MIDX(t, p)]) + bf2f(Ml[MIDX(t, p)]), Bv[p], a2);
      float v = 0.5f * step * (a2 + Bv[t]);
      u16 h = f2bf(v);
      rt[t] = h;
      rt[32768 + t] = f2bf(v - bf2f(h));
    }
    for (int k = 0; k < 8; ++k) {
      mm<0,1,0,2,0>(lds, 0,0, rt,32768, rt,32768,(1<<k),0, 128,(1<<k), 0.f, 0,0);
      if (k < 7) mm<0,0,2,0,0>(lds, 0,0, 0,0, 0,0,0,0, 128,128, 0.f, 0,0);
    }
  } else {
    __syncthreads();
    if (t < 128) {  // S row 0 = C
      float v = Cv[t];
      u16 h = f2bf(v);
      gs[t] = h;
      gs[GP + t] = f2bf(v - bf2f(h));
    }
    for (int k = 0; k < 8; ++k)
      mm<0,0,2,0,0>(lds, 0,0, 0,0, 0,0,0,0, 128,128, 0.f, 0,0);             // -> pw8
    for (int k = 0; k < 7; ++k) {
      mm<1,0,0,1,0>(lds, gs,GP, 0,0, gs,GP,(1<<k),0, (1<<k),128, 0.f, 0,0);
      if (k < 6) mm<0,0,2,0,0>(lds, 0,0, 0,0, 0,0,0,0, 128,128, 0.f, 0,0);
    }
  }
}

// ---------------------------------------------------------------------------
// K[t1*256 + t0] = S[t1] . R[:,t0]  (plain rows both sides)
// ---------------------------------------------------------------------------
__global__ __launch_bounds__(256) void kmat_k(const u16* __restrict__ gs,
                                              const u16* __restrict__ rt,
                                              float* __restrict__ Kv) {
  __shared__ float srow[128];
  int t1 = blockIdx.x, t0 = threadIdx.x;
  if (t0 < 128)
    srow[t0] = bf2f(gs[t1 * 128 + t0]) + bf2f(gs[GP + t1 * 128 + t0]);
  __syncthreads();
  const u16* rh = rt + t0 * 128;
  const u16* rl = rt + 32768 + t0 * 128;
  float acc = 0.f;
#pragma unroll 4
  for (int p = 0; p < 128; p += 8) {
    uint4 qh = *(const uint4*)(rh + p);
    uint4 ql = *(const uint4*)(rl + p);
    unsigned dh[4] = {qh.x, qh.y, qh.z, qh.w};
    unsigned dl[4] = {ql.x, ql.y, ql.z, ql.w};
#pragma unroll
    for (int j = 0; j < 4; ++j) {
      acc = fmaf(srow[p + 2 * j],     bf2f((u16)dh[j]) + bf2f((u16)dl[j]), acc);
      acc = fmaf(srow[p + 2 * j + 1],
                 bf2f((u16)(dh[j] >> 16)) + bf2f((u16)(dl[j] >> 16)), acc);
    }
  }
  Kv[t1 * 256 + t0] = acc;
}

// ---------------------------------------------------------------------------
// Conv partials. TS=512: task (m,c), c<=m, m<64 -> 2080 blocks (~8/CU).
// 128 thr x 4 outputs. XOR-swizzled LDS, register window shift.
// Output packed by task id: Pp[bid*512 + i].
// ---------------------------------------------------------------------------
__global__ __launch_bounds__(128) void conv_k(const float* __restrict__ u,
                                              const float* __restrict__ Kv,
                                              float* __restrict__ Pp) {
  __shared__ __align__(16) float ks[512];
  __shared__ __align__(16) float usw[1024];

  int bid = blockIdx.x, tid = threadIdx.x;
  int m = (int)((sqrtf(8.f * (float)bid + 1.f) - 1.f) * 0.5f);
  while ((m + 1) * (m + 2) / 2 <= bid) ++m;
  while (m * (m + 1) / 2 > bid) --m;
  int c = bid - m * (m + 1) / 2;
  int w0 = (m - c - 1) << 9;   // logical us[li] = u[w0 + li]

  for (int idx = tid; idx < 512; idx += 128) ks[idx] = Kv[(c << 9) + idx];
  for (int idx = tid; idx < 1024; idx += 128) {
    int gi = w0 + idx;
    float v = (gi >= 0) ? u[gi] : 0.f;
    int b = idx >> 2;
    int pb = b ^ ((b >> 3) & 7);
    usw[(pb << 2) | (idx & 3)] = v;
  }
  __syncthreads();

  int tb = tid << 2;

#define LD4(x)                                                      \
  (*(const float4*)&usw[((((x) >> 2) ^ ((((x) >> 2) >> 3) & 7)) << 2)])

  float4 wlo = LD4(508 + tb);
  float4 whi = LD4(512 + tb);
  float acc0 = 0.f, acc1 = 0.f, acc2 = 0.f, acc3 = 0.f;

#pragma unroll 4
  for (int s8 = 0; s8 < 512; s8 += 4) {
    float4 k4 = *(const float4*)&ks[s8];
    acc0 = fmaf(k4.x, whi.x, acc0);
    acc0 = fmaf(k4.y, wlo.w, acc0);
    acc0 = fmaf(k4.z, wlo.z, acc0);
    acc0 = fmaf(k4.w, wlo.y, acc0);
    acc1 = fmaf(k4.x, whi.y, acc1);
    acc1 = fmaf(k4.y, whi.x, acc1);
    acc1 = fmaf(k4.z, wlo.w, acc1);
    acc1 = fmaf(k4.w, wlo.z, acc1);
    acc2 = fmaf(k4.x, whi.z, acc2);
    acc2 = fmaf(k4.y, whi.y, acc2);
    acc2 = fmaf(k4.z, whi.x, acc2);
    acc2 = fmaf(k4.w, wlo.w, acc2);
    acc3 = fmaf(k4.x, whi.w, acc3);
    acc3 = fmaf(k4.y, whi.z, acc3);
    acc3 = fmaf(k4.z, whi.y, acc3);
    acc3 = fmaf(k4.w, whi.x, acc3);
    if (s8 < 508) {
      whi = wlo;
      wlo = LD4(504 + tb - s8);
    }
  }
#undef LD4

  float* dst = Pp + (bid << 9) + tb;
  *(float4*)dst = make_float4(acc0, acc1, acc2, acc3);
}

// ---------------------------------------------------------------------------
// reduce: y[t] = D*u[t] + sum_{c<=m} Pp[(T(m)+c)*512 + (t&511)], m = t>>9
// ---------------------------------------------------------------------------
__global__ __launch_bounds__(256) void reduce_k(const float* __restrict__ Pp,
                                                const float* __restrict__ u,
                                                const float* __restrict__ D,
                                                float* __restrict__ y) {
  int t = blockIdx.x * 256 + threadIdx.x;
  if (t >= L_SEQ) return;
  int m = t >> 9;
  int base = ((m * (m + 1) / 2) << 9) + (t & 511);
  float acc = D[0] * u[t];
  for (int c = 0; c <= m; ++c) acc += Pp[base + (c << 9)];
  y[t] = acc;
}

// ---------------------------------------------------------------------------
// host side. ws layout (bytes):
//   [0, 524288)        per-block Neumann spills (2 x 131072 u16)
//   [524288, 655360)   rt (R^T) 2 planes of 32768 u16
//   [655360, 720896)   gs (S)   2 planes of 16384 u16
//   [720896, 851968)   Kv f32[32768]
//   [851968, 5111808)  Pp f32[2080*512]
// ---------------------------------------------------------------------------
extern "C" void kernel_launch(void* const* d_in, const int* in_sizes, int n_in,
                              void* d_out, int out_size, void* d_ws, size_t ws_size,
                              hipStream_t stream) {
  (void)in_sizes; (void)n_in; (void)out_size; (void)ws_size;
  const float* u     = (const float*)d_in[0];
  const float* A     = (const float*)d_in[1];
  const float* B     = (const float*)d_in[2];
  const float* C     = (const float*)d_in[3];
  const float* D     = (const float*)d_in[4];
  const float* lstep = (const float*)d_in[5];
  float* y = (float*)d_out;
  u16* ws = (u16*)d_ws;

  u16* rt = ws + 262144;
  u16* gs = ws + 327680;
  float* Kv = (float*)((char*)d_ws + 720896);
  float* Pp = (float*)((char*)d_ws + 851968);

  (void)hipFuncSetAttribute((const void*)chain_k,
                            hipFuncAttributeMaxDynamicSharedMemorySize, 131072);
  hipLaunchKernelGGL(chain_k, dim3(2), dim3(1024), 131072, stream, A, B, C, lstep, ws);
  hipLaunchKernelGGL(kmat_k, dim3(128), dim3(256), 0, stream, gs, rt, Kv);
  hipLaunchKernelGGL(conv_k, dim3(2080), dim3(128), 0, stream, u, Kv, Pp);
  hipLaunchKernelGGL(reduce_k, dim3(L_SEQ / 256), dim3(256), 0, stream, Pp, u, D, y);
}